// Round 8
// baseline (377.017 us; speedup 1.0000x reference)
//
#include <hip/hip_runtime.h>

#define NN 50000
#define NE 800000
#define NBLK ((NN + 255) / 256)   // 196 scan blocks

// ---------------- CSR build ----------------
__global__ __launch_bounds__(256) void zero_cnt_k(int* __restrict__ cnt) {
    int i = blockIdx.x * blockDim.x + threadIdx.x;
    if (i < NN) cnt[i] = 0;
}

__global__ __launch_bounds__(256) void hist_k(const int* __restrict__ dst, int* __restrict__ cnt) {
    int e = blockIdx.x * blockDim.x + threadIdx.x;
    if (e < NE) atomicAdd(&cnt[dst[e]], 1);
}

// ---- hierarchical scan: cnt -> rowstart (exclusive), then cnt := 0 ----
// phase 1: per-block sums; also computes dinv = rsqrt(deg+1)
__global__ __launch_bounds__(256) void sum_blocks_k(const int* __restrict__ cnt,
                                                    int* __restrict__ bsum,
                                                    float* __restrict__ dinv) {
    __shared__ int s[256];
    int t = threadIdx.x;
    int i = blockIdx.x * 256 + t;
    int v = (i < NN) ? cnt[i] : 0;
    s[t] = v;
    if (i < NN) dinv[i] = rsqrtf((float)(v + 1));  // +1 self loop
    __syncthreads();
    for (int off = 128; off > 0; off >>= 1) {
        if (t < off) s[t] += s[t + off];
        __syncthreads();
    }
    if (t == 0) bsum[blockIdx.x] = s[0];
}

// phase 2: exclusive scan of NBLK block sums; zero degree-histogram bins
__global__ __launch_bounds__(256) void scan_blocks_k(int* __restrict__ bsum,
                                                     int* __restrict__ rowstart,
                                                     int* __restrict__ dbin) {
    __shared__ int s[256];
    int t = threadIdx.x;
    int v = (t < NBLK) ? bsum[t] : 0;
    s[t] = v;
    dbin[t] = 0;
    __syncthreads();
    for (int off = 1; off < 256; off <<= 1) {
        int x = (t >= off) ? s[t - off] : 0;
        __syncthreads();
        s[t] += x;
        __syncthreads();
    }
    if (t < NBLK) bsum[t] = s[t] - v;  // exclusive
    if (t == 0) rowstart[NN] = NE;
}

// phase 3: per-block exclusive scan + block offset; zero cnt for cursor reuse;
// LDS-aggregated degree histogram -> dbin
__global__ __launch_bounds__(256) void scan_final_k(int* __restrict__ cnt,
                                                    const int* __restrict__ bsum,
                                                    int* __restrict__ rowstart,
                                                    int* __restrict__ dbin) {
    __shared__ int s[256];
    __shared__ int hb[256];
    int t = threadIdx.x;
    int i = blockIdx.x * 256 + t;
    int v = (i < NN) ? cnt[i] : 0;
    s[t] = v;
    hb[t] = 0;
    __syncthreads();
    for (int off = 1; off < 256; off <<= 1) {
        int x = (t >= off) ? s[t - off] : 0;
        __syncthreads();
        s[t] += x;
        __syncthreads();
    }
    if (i < NN) {
        rowstart[i] = bsum[blockIdx.x] + s[t] - v;  // exclusive
        cnt[i] = 0;
        atomicAdd(&hb[min(v, 255)], 1);
    }
    __syncthreads();
    if (hb[t]) atomicAdd(&dbin[t], hb[t]);
}

// suffix-exclusive scan of degree bins (descending-degree order) + zero cursors
__global__ __launch_bounds__(256) void dscan_k(const int* __restrict__ dbin,
                                               int* __restrict__ dstart,
                                               int* __restrict__ dcur) {
    __shared__ int s[256];
    int t = threadIdx.x;
    int v = dbin[t];
    s[t] = v;
    dcur[t] = 0;
    __syncthreads();
    for (int off = 1; off < 256; off <<= 1) {
        int x = (t + off < 256) ? s[t + off] : 0;
        __syncthreads();
        s[t] += x;
        __syncthreads();
    }
    dstart[t] = s[t] - v;  // sum of bins with degree > t
}

// block-aggregated counting-sort scatter: perm = node ids, descending degree
__global__ __launch_bounds__(256) void dperm_k(const int* __restrict__ rowstart,
                                               const int* __restrict__ dstart,
                                               int* __restrict__ dcur,
                                               int* __restrict__ perm) {
    __shared__ int hcnt[256];
    __shared__ int hbase[256];
    int t = threadIdx.x;
    int i = blockIdx.x * 256 + t;
    hcnt[t] = 0;
    __syncthreads();
    int bin = 0, myrank = 0;
    if (i < NN) {
        int deg = rowstart[i + 1] - rowstart[i];
        bin = min(deg, 255);
        myrank = atomicAdd(&hcnt[bin], 1);
    }
    __syncthreads();
    if (hcnt[t]) hbase[t] = atomicAdd(&dcur[t], hcnt[t]);
    __syncthreads();
    if (i < NN) perm[dstart[bin] + hbase[bin] + myrank] = i;
}

// packs (col, weight) into int2 for a single 8B load per edge in prop
__global__ __launch_bounds__(256) void scatter_k(const int* __restrict__ src,
                                                 const int* __restrict__ dst,
                                                 const int* __restrict__ rowstart,
                                                 int* __restrict__ cursor,
                                                 const float* __restrict__ dinv,
                                                 int2* __restrict__ colw) {
    int e = blockIdx.x * blockDim.x + threadIdx.x;
    if (e >= NE) return;
    int s = src[e], d = dst[e];
    int pos = rowstart[d] + atomicAdd(&cursor[d], 1);
    colw[pos] = make_int2(s, __float_as_int(dinv[s] * dinv[d]));
}

// ---------------- propagation (CSR, dst-stationary, degree-sorted) ----------------
// node = perm[node_idx]: waves carry equal-degree nodes -> no max-degree divergence.
template<int LOG2C4, bool ADDIN>
__global__ __launch_bounds__(256) void prop_k(const float4* __restrict__ h4,
                                              const float4* __restrict__ addin4,
                                              const float* __restrict__ bias,
                                              float4* __restrict__ out4,
                                              const int* __restrict__ rowstart,
                                              const int2* __restrict__ colw,
                                              const float* __restrict__ dinv,
                                              const int* __restrict__ perm) {
    const int C4 = 1 << LOG2C4;
    unsigned tid = blockIdx.x * blockDim.x + threadIdx.x;
    unsigned node_idx = tid >> LOG2C4;
    if (node_idx >= NN) return;
    int node = perm[node_idx];
    unsigned lane = tid & (C4 - 1);
    size_t rowoff = ((size_t)node << LOG2C4) + lane;
    float w0 = dinv[node];
    w0 *= w0;
    float4 hv = h4[rowoff];
    float4 acc;
    if (ADDIN) {
        float4 a = addin4[rowoff];
        acc.x = a.x + w0 * hv.x; acc.y = a.y + w0 * hv.y;
        acc.z = a.z + w0 * hv.z; acc.w = a.w + w0 * hv.w;
    } else {
        float4 b = ((const float4*)bias)[lane];
        acc.x = b.x + w0 * hv.x; acc.y = b.y + w0 * hv.y;
        acc.z = b.z + w0 * hv.z; acc.w = b.w + w0 * hv.w;
    }
    int rs = rowstart[node], re = rowstart[node + 1];
    int i = rs;
    for (; i + 4 <= re; i += 4) {
        int2 cw0 = colw[i];
        int2 cw1 = colw[i + 1];
        int2 cw2 = colw[i + 2];
        int2 cw3 = colw[i + 3];
        float4 v0 = h4[((size_t)cw0.x << LOG2C4) + lane];
        float4 v1 = h4[((size_t)cw1.x << LOG2C4) + lane];
        float4 v2 = h4[((size_t)cw2.x << LOG2C4) + lane];
        float4 v3 = h4[((size_t)cw3.x << LOG2C4) + lane];
        float a0 = __int_as_float(cw0.y);
        float a1 = __int_as_float(cw1.y);
        float a2 = __int_as_float(cw2.y);
        float a3 = __int_as_float(cw3.y);
        acc.x += a0 * v0.x + a1 * v1.x + a2 * v2.x + a3 * v3.x;
        acc.y += a0 * v0.y + a1 * v1.y + a2 * v2.y + a3 * v3.y;
        acc.z += a0 * v0.z + a1 * v1.z + a2 * v2.z + a3 * v3.z;
        acc.w += a0 * v0.w + a1 * v1.w + a2 * v2.w + a3 * v3.w;
    }
    for (; i < re; i++) {
        int2 cw = colw[i];
        float4 v = h4[((size_t)cw.x << LOG2C4) + lane];
        float w = __int_as_float(cw.y);
        acc.x += w * v.x; acc.y += w * v.y; acc.z += w * v.z; acc.w += w * v.w;
    }
    if (!ADDIN) {
        acc.x = fmaxf(acc.x, 0.0f); acc.y = fmaxf(acc.y, 0.0f);
        acc.z = fmaxf(acc.z, 0.0f); acc.w = fmaxf(acc.w, 0.0f);
    }
    out4[rowoff] = acc;
}

// ---------------- layer-1 GEMM: [outA|outB] = A @ [WA|WB], K=128, both mats ----------------
__global__ __launch_bounds__(256) void gemm1_k(const float* __restrict__ A,
                                               const float* __restrict__ WA,
                                               const float* __restrict__ WB,
                                               float* __restrict__ outA,
                                               float* __restrict__ outB, int n) {
    __shared__ float As[64 * 68];
    __shared__ float W1s[64 * 68];
    __shared__ float W2s[64 * 68];
    const int t = threadIdx.x;
    const int tj = t & 15;
    const int tn = t >> 4;
    const int n0 = blockIdx.x * 64;
    float acc[4][8] = {};

    for (int kc = 0; kc < 128; kc += 64) {
        if (kc) __syncthreads();
        {
            int idx = t;
#pragma unroll
            for (int r = 0; r < 4; r++, idx += 256) {
                int nl = idx >> 4, q = idx & 15;
                int node = n0 + nl; node = node < n ? node : n - 1;
                float4 a = ((const float4*)A)[(size_t)node * 32 + (kc >> 2) + q];
                *(float4*)&As[nl * 68 + q * 4] = a;
            }
        }
        {
            int idx = t;
#pragma unroll
            for (int r = 0; r < 4; r++, idx += 256) {
                int kl = idx >> 4, j4 = idx & 15;
                *(float4*)&W1s[kl * 68 + j4 * 4] = ((const float4*)WA)[(size_t)(kc + kl) * 16 + j4];
                *(float4*)&W2s[kl * 68 + j4 * 4] = ((const float4*)WB)[(size_t)(kc + kl) * 16 + j4];
            }
        }
        __syncthreads();

        const float* ap = &As[tn * 4 * 68];
        const float* w1p = &W1s[tj * 4];
        const float* w2p = &W2s[tj * 4];
#pragma unroll 2
        for (int k4 = 0; k4 < 16; k4++) {
            float4 a0 = *(const float4*)&ap[0 * 68 + k4 * 4];
            float4 a1 = *(const float4*)&ap[1 * 68 + k4 * 4];
            float4 a2 = *(const float4*)&ap[2 * 68 + k4 * 4];
            float4 a3 = *(const float4*)&ap[3 * 68 + k4 * 4];
#pragma unroll
            for (int kk = 0; kk < 4; kk++) {
                float4 w1 = *(const float4*)&w1p[(k4 * 4 + kk) * 68];
                float4 w2 = *(const float4*)&w2p[(k4 * 4 + kk) * 68];
                float av0 = kk == 0 ? a0.x : kk == 1 ? a0.y : kk == 2 ? a0.z : a0.w;
                float av1 = kk == 0 ? a1.x : kk == 1 ? a1.y : kk == 2 ? a1.z : a1.w;
                float av2 = kk == 0 ? a2.x : kk == 1 ? a2.y : kk == 2 ? a2.z : a2.w;
                float av3 = kk == 0 ? a3.x : kk == 1 ? a3.y : kk == 2 ? a3.z : a3.w;
#define FMA8(m, AV)                                                     \
                acc[m][0] += AV * w1.x; acc[m][1] += AV * w1.y;          \
                acc[m][2] += AV * w1.z; acc[m][3] += AV * w1.w;          \
                acc[m][4] += AV * w2.x; acc[m][5] += AV * w2.y;          \
                acc[m][6] += AV * w2.z; acc[m][7] += AV * w2.w;
                FMA8(0, av0)
                FMA8(1, av1)
                FMA8(2, av2)
                FMA8(3, av3)
#undef FMA8
            }
        }
    }

#pragma unroll
    for (int m = 0; m < 4; m++) {
        int node = n0 + tn * 4 + m;
        if (node < n) {
            *(float4*)&outA[(size_t)node * 64 + tj * 4] =
                make_float4(acc[m][0], acc[m][1], acc[m][2], acc[m][3]);
            *(float4*)&outB[(size_t)node * 64 + tj * 4] =
                make_float4(acc[m][4], acc[m][5], acc[m][6], acc[m][7]);
        }
    }
}

// ---------------- layer-2 GEMM: out = A @ [WA|WB], K=64, JW=32 ----------------
template<int K, int JW>
__global__ __launch_bounds__(256) void gemm_k(const float* __restrict__ A,
                                              const float* __restrict__ WA,
                                              const float* __restrict__ WB,
                                              float* __restrict__ out, int n) {
    __shared__ float As[64 * 68];
    __shared__ float Ws[64 * 68];
    const int t = threadIdx.x;
    const int tj = t & 15;
    const int tn = t >> 4;
    const int n0 = blockIdx.x * 64;
    float acc[4][4] = {};

    for (int kc = 0; kc < K; kc += 64) {
        if (kc) __syncthreads();
        {
            int idx = t;
#pragma unroll
            for (int r = 0; r < 4; r++, idx += 256) {
                int nl = idx >> 4, q = idx & 15;
                int node = n0 + nl; node = node < n ? node : n - 1;
                float4 a = ((const float4*)A)[(size_t)node * (K / 4) + (kc >> 2) + q];
                *(float4*)&As[nl * 68 + q * 4] = a;
            }
        }
        {
            int idx = t;
#pragma unroll
            for (int r = 0; r < 4; r++, idx += 256) {
                int kl = idx >> 4, j4 = idx & 15;
                const float* W = (j4 < 8) ? WA : WB;
                float4 w = ((const float4*)W)[(size_t)(kc + kl) * 8 + (j4 & 7)];
                *(float4*)&Ws[kl * 68 + j4 * 4] = w;
            }
        }
        __syncthreads();

        const float* ap = &As[tn * 4 * 68];
        const float* wp = &Ws[tj * 4];
#pragma unroll 4
        for (int k4 = 0; k4 < 16; k4++) {
            float4 a0 = *(const float4*)&ap[0 * 68 + k4 * 4];
            float4 a1 = *(const float4*)&ap[1 * 68 + k4 * 4];
            float4 a2 = *(const float4*)&ap[2 * 68 + k4 * 4];
            float4 a3 = *(const float4*)&ap[3 * 68 + k4 * 4];
            float4 w0 = *(const float4*)&wp[(k4 * 4 + 0) * 68];
            float4 w1 = *(const float4*)&wp[(k4 * 4 + 1) * 68];
            float4 w2 = *(const float4*)&wp[(k4 * 4 + 2) * 68];
            float4 w3 = *(const float4*)&wp[(k4 * 4 + 3) * 68];
#define FMA_ROW(m, AV)                                                   \
            acc[m][0] += AV.x * w0.x + AV.y * w1.x + AV.z * w2.x + AV.w * w3.x; \
            acc[m][1] += AV.x * w0.y + AV.y * w1.y + AV.z * w2.y + AV.w * w3.y; \
            acc[m][2] += AV.x * w0.z + AV.y * w1.z + AV.z * w2.z + AV.w * w3.z; \
            acc[m][3] += AV.x * w0.w + AV.y * w1.w + AV.z * w2.w + AV.w * w3.w;
            FMA_ROW(0, a0)
            FMA_ROW(1, a1)
            FMA_ROW(2, a2)
            FMA_ROW(3, a3)
#undef FMA_ROW
        }
    }

    int mat = tj >> 3;
    int jw = (tj & 7) * 4;
    float* ob = out + (size_t)mat * n * JW + jw;
#pragma unroll
    for (int m = 0; m < 4; m++) {
        int node = n0 + tn * 4 + m;
        if (node < n)
            *(float4*)&ob[(size_t)node * JW] =
                make_float4(acc[m][0], acc[m][1], acc[m][2], acc[m][3]);
    }
}

// ---------------- fused heads, 8 threads/node ----------------
__global__ __launch_bounds__(256) void heads_k(const float* __restrict__ h2,
                                               const float* __restrict__ Wp1, const float* __restrict__ bp1,
                                               const float* __restrict__ Wp2, const float* __restrict__ bp2,
                                               const float* __restrict__ Wc1, const float* __restrict__ bc1,
                                               const float* __restrict__ Wc2, const float* __restrict__ bc2,
                                               float* __restrict__ coord, float* __restrict__ z, int n) {
    __shared__ float sWp1[32 * 32], sWp2[32 * 32], sWc1[32 * 16], sWc2[32];
    __shared__ float sbp1[32], sbp2[32], sbc1[16], sbc2[2];
    __shared__ float sh[32 * 36], st[32 * 36], stc[32 * 18];
    const int t = threadIdx.x;
    for (int i = t; i < 1024; i += 256) { sWp1[i] = Wp1[i]; sWp2[i] = Wp2[i]; }
    for (int i = t; i < 512; i += 256) sWc1[i] = Wc1[i];
    if (t < 32) { sWc2[t] = Wc2[t]; sbp1[t] = bp1[t]; sbp2[t] = bp2[t]; }
    if (t < 16) sbc1[t] = bc1[t];
    if (t < 2) sbc2[t] = bc2[t];

    const int n0 = blockIdx.x * 32;
    const int nl = t >> 3;
    const int jq = t & 7;
    const int node = n0 + nl;
    {
        float4 v = make_float4(0.f, 0.f, 0.f, 0.f);
        if (node < n) v = *(const float4*)&h2[(size_t)node * 32 + jq * 4];
        *(float4*)&sh[nl * 36 + jq * 4] = v;
    }
    __syncthreads();

    float4 a = *(const float4*)&sbp1[jq * 4];
#pragma unroll
    for (int k = 0; k < 32; k++) {
        float hv = sh[nl * 36 + k];
        float4 w = *(const float4*)&sWp1[k * 32 + jq * 4];
        a.x += hv * w.x; a.y += hv * w.y; a.z += hv * w.z; a.w += hv * w.w;
    }
    a.x = fmaxf(a.x, 0.f); a.y = fmaxf(a.y, 0.f);
    a.z = fmaxf(a.z, 0.f); a.w = fmaxf(a.w, 0.f);
    *(float4*)&st[nl * 36 + jq * 4] = a;

    float2 c = *(const float2*)&sbc1[jq * 2];
#pragma unroll
    for (int k = 0; k < 32; k++) {
        float hv = sh[nl * 36 + k];
        float2 w = *(const float2*)&sWc1[k * 16 + jq * 2];
        c.x += hv * w.x; c.y += hv * w.y;
    }
    c.x = fmaxf(c.x, 0.f); c.y = fmaxf(c.y, 0.f);
    *(float2*)&stc[nl * 18 + jq * 2] = c;
    __syncthreads();

    float4 zz = *(const float4*)&sbp2[jq * 4];
#pragma unroll
    for (int k = 0; k < 32; k++) {
        float tv = st[nl * 36 + k];
        float4 w = *(const float4*)&sWp2[k * 32 + jq * 4];
        zz.x += tv * w.x; zz.y += tv * w.y; zz.z += tv * w.z; zz.w += tv * w.w;
    }
    if (node < n) *(float4*)&z[(size_t)node * 32 + jq * 4] = zz;

    if (jq < 2) {
        float s = sbc2[jq];
#pragma unroll
        for (int k = 0; k < 16; k++) s += stc[nl * 18 + k] * sWc2[k * 2 + jq];
        if (node < n) coord[(size_t)node * 2 + jq] = s;
    }
}

extern "C" void kernel_launch(void* const* d_in, const int* in_sizes, int n_in,
                              void* d_out, int out_size, void* d_ws, size_t ws_size,
                              hipStream_t stream) {
    const float* x    = (const float*)d_in[0];
    const int*   ei   = (const int*)d_in[1];
    const int*   src  = ei;
    const int*   dst  = ei + NE;
    const float* W1_1 = (const float*)d_in[2];
    const float* W1_2 = (const float*)d_in[3];
    const float* b1   = (const float*)d_in[4];
    const float* W2_1 = (const float*)d_in[5];
    const float* W2_2 = (const float*)d_in[6];
    const float* b2   = (const float*)d_in[7];
    const float* Wp1  = (const float*)d_in[8];
    const float* bp1  = (const float*)d_in[9];
    const float* Wp2  = (const float*)d_in[10];
    const float* bp2  = (const float*)d_in[11];
    const float* Wc1  = (const float*)d_in[12];
    const float* bc1  = (const float*)d_in[13];
    const float* Wc2  = (const float*)d_in[14];
    const float* bc2  = (const float*)d_in[15];

    // workspace layout (4-byte words; bufY offset padded to 16B alignment)
    float* ws     = (float*)d_ws;
    float* dinv   = ws;                             // NN
    int*   cnt    = (int*)(dinv + NN);              // NN
    int*   rows   = cnt + NN;                       // NN+2
    int*   bsum   = rows + NN + 2;                  // NBLK (pad to 256)
    int*   dbin   = bsum + 256;                     // 256
    int*   dstart = dbin + 256;                     // 256
    int*   dcur   = dstart + 256;                   // 256
    int*   perm   = dcur + 256;                     // NN
    int2*  colw   = (int2*)(perm + NN);             // NE int2 (offset even -> 8B aligned)
    float* bufY   = (float*)(colw + NE) + 2;        // +2 words -> 16B aligned; NN*128
    float* bufZ   = bufY + (size_t)NN * 128;        // NN*64

    float* y1 = bufY;                       // NN*64   (then reused as u)
    float* y2 = bufY + (size_t)NN * 64;     // NN*64   (then reused as h1)
    float* u  = y1;
    float* h1 = y2;
    float* z1 = bufZ;                       // NN*32   (then reused as u2)
    float* z2 = bufZ + (size_t)NN * 32;     // NN*32   (then reused as h2)
    float* u2 = z1;
    float* h2 = z2;

    float* coord = (float*)d_out;                   // NN*2
    float* z     = (float*)d_out + 2 * NN;          // NN*32

    // 1) CSR build + dinv + degree-sorted permutation
    zero_cnt_k<<<(NN + 255) / 256, 256, 0, stream>>>(cnt);
    hist_k<<<(NE + 255) / 256, 256, 0, stream>>>(dst, cnt);
    sum_blocks_k<<<NBLK, 256, 0, stream>>>(cnt, bsum, dinv);
    scan_blocks_k<<<1, 256, 0, stream>>>(bsum, rows, dbin);
    scan_final_k<<<NBLK, 256, 0, stream>>>(cnt, bsum, rows, dbin);
    scatter_k<<<(NE + 255) / 256, 256, 0, stream>>>(src, dst, rows, cnt, dinv, colw);
    dscan_k<<<1, 256, 0, stream>>>(dbin, dstart, dcur);
    dperm_k<<<NBLK, 256, 0, stream>>>(rows, dstart, dcur, perm);

    // 2) [y1|y2] = x @ [W1_1|W1_2]   (K=128, both matrices in one pass)
    gemm1_k<<<(NN + 63) / 64, 256, 0, stream>>>(x, W1_1, W1_2, y1, y2, NN);
    // 3) u = y1 + P(y2)              (C=64)
    prop_k<4, true><<<(NN * 16 + 255) / 256, 256, 0, stream>>>(
        (const float4*)y2, (const float4*)y1, nullptr, (float4*)u, rows, colw, dinv, perm);
    // 4) h1 = relu(P(u) + b1)        (C=64)
    prop_k<4, false><<<(NN * 16 + 255) / 256, 256, 0, stream>>>(
        (const float4*)u, nullptr, b1, (float4*)h1, rows, colw, dinv, perm);
    // 5) [z1|z2] = h1 @ [W2_1|W2_2]  (K=64, one block spans both 32-wide mats)
    gemm_k<64, 32><<<(NN + 63) / 64, 256, 0, stream>>>(h1, W2_1, W2_2, bufZ, NN);
    // 6) u2 = z1 + P(z2)             (C=32)
    prop_k<3, true><<<(NN * 8 + 255) / 256, 256, 0, stream>>>(
        (const float4*)z2, (const float4*)z1, nullptr, (float4*)u2, rows, colw, dinv, perm);
    // 7) h2 = relu(P(u2) + b2)       (C=32)
    prop_k<3, false><<<(NN * 8 + 255) / 256, 256, 0, stream>>>(
        (const float4*)u2, nullptr, b2, (float4*)h2, rows, colw, dinv, perm);
    // 8) heads (8 threads/node)
    heads_k<<<(NN + 31) / 32, 256, 0, stream>>>(h2, Wp1, bp1, Wp2, bp2, Wc1, bc1, Wc2, bc2, coord, z, NN);
}

// Round 9
// 329.412 us; speedup vs baseline: 1.1445x; 1.1445x over previous
//
#include <hip/hip_runtime.h>

#define NN 50000
#define NE 800000
#define NBLK ((NN + 255) / 256)   // 196 scan blocks

// ---------------- CSR build ----------------
__global__ __launch_bounds__(256) void zero_cnt_k(int* __restrict__ cnt) {
    int i = blockIdx.x * blockDim.x + threadIdx.x;
    if (i < NN) cnt[i] = 0;
}

// histogram + per-edge rank within its dst row (atomic return value)
__global__ __launch_bounds__(256) void hist_k(const int* __restrict__ dst,
                                              int* __restrict__ cnt,
                                              int* __restrict__ rank) {
    int e = blockIdx.x * blockDim.x + threadIdx.x;
    if (e < NE) rank[e] = atomicAdd(&cnt[dst[e]], 1);
}

// ---- hierarchical scan: cnt -> rowstart (exclusive) ----
// phase 1: per-block sums; also computes dinv = rsqrt(deg+1)
__global__ __launch_bounds__(256) void sum_blocks_k(const int* __restrict__ cnt,
                                                    int* __restrict__ bsum,
                                                    float* __restrict__ dinv) {
    __shared__ int s[256];
    int t = threadIdx.x;
    int i = blockIdx.x * 256 + t;
    int v = (i < NN) ? cnt[i] : 0;
    s[t] = v;
    if (i < NN) dinv[i] = rsqrtf((float)(v + 1));  // +1 self loop
    __syncthreads();
    for (int off = 128; off > 0; off >>= 1) {
        if (t < off) s[t] += s[t + off];
        __syncthreads();
    }
    if (t == 0) bsum[blockIdx.x] = s[0];
}

// phase 2: exclusive scan of NBLK block sums (single tiny block), plus tail
__global__ __launch_bounds__(256) void scan_blocks_k(int* __restrict__ bsum,
                                                     int* __restrict__ rowstart) {
    __shared__ int s[256];
    int t = threadIdx.x;
    int v = (t < NBLK) ? bsum[t] : 0;
    s[t] = v;
    __syncthreads();
    for (int off = 1; off < 256; off <<= 1) {
        int x = (t >= off) ? s[t - off] : 0;
        __syncthreads();
        s[t] += x;
        __syncthreads();
    }
    if (t < NBLK) bsum[t] = s[t] - v;  // exclusive
    if (t == 0) rowstart[NN] = NE;
}

// phase 3: per-block exclusive scan + block offset
__global__ __launch_bounds__(256) void scan_final_k(const int* __restrict__ cnt,
                                                    const int* __restrict__ bsum,
                                                    int* __restrict__ rowstart) {
    __shared__ int s[256];
    int t = threadIdx.x;
    int i = blockIdx.x * 256 + t;
    int v = (i < NN) ? cnt[i] : 0;
    s[t] = v;
    __syncthreads();
    for (int off = 1; off < 256; off <<= 1) {
        int x = (t >= off) ? s[t - off] : 0;
        __syncthreads();
        s[t] += x;
        __syncthreads();
    }
    if (i < NN) rowstart[i] = bsum[blockIdx.x] + s[t] - v;  // exclusive
}

// atomic-free scatter: position known from rowstart + precomputed rank
__global__ __launch_bounds__(256) void scatter_k(const int* __restrict__ src,
                                                 const int* __restrict__ dst,
                                                 const int* __restrict__ rank,
                                                 const int* __restrict__ rowstart,
                                                 int* __restrict__ col) {
    int e = blockIdx.x * blockDim.x + threadIdx.x;
    if (e >= NE) return;
    col[rowstart[dst[e]] + rank[e]] = src[e];
}

// ---------------- propagation (CSR, dst-stationary) ----------------
// weight computed inline: w = dinv[col] * dinv[node] (bit-identical to packed).
// 4-wide edge unroll keeps 4 independent 256B gathers in flight per thread.
template<int LOG2C4, bool ADDIN>
__global__ __launch_bounds__(256) void prop_k(const float4* __restrict__ h4,
                                              const float4* __restrict__ addin4,
                                              const float* __restrict__ bias,
                                              float4* __restrict__ out4,
                                              const int* __restrict__ rowstart,
                                              const int* __restrict__ col,
                                              const float* __restrict__ dinv) {
    const int C4 = 1 << LOG2C4;
    unsigned tid = blockIdx.x * blockDim.x + threadIdx.x;
    unsigned node = tid >> LOG2C4;
    if (node >= NN) return;
    unsigned lane = tid & (C4 - 1);
    size_t rowoff = ((size_t)node << LOG2C4) + lane;
    float dn = dinv[node];
    float w0 = dn * dn;
    float4 hv = h4[rowoff];
    float4 acc;
    if (ADDIN) {
        float4 a = addin4[rowoff];
        acc.x = a.x + w0 * hv.x; acc.y = a.y + w0 * hv.y;
        acc.z = a.z + w0 * hv.z; acc.w = a.w + w0 * hv.w;
    } else {
        float4 b = ((const float4*)bias)[lane];
        acc.x = b.x + w0 * hv.x; acc.y = b.y + w0 * hv.y;
        acc.z = b.z + w0 * hv.z; acc.w = b.w + w0 * hv.w;
    }
    int rs = rowstart[node], re = rowstart[node + 1];
    int i = rs;
    for (; i + 4 <= re; i += 4) {
        int c0 = col[i];
        int c1 = col[i + 1];
        int c2 = col[i + 2];
        int c3 = col[i + 3];
        float4 v0 = h4[((size_t)c0 << LOG2C4) + lane];
        float4 v1 = h4[((size_t)c1 << LOG2C4) + lane];
        float4 v2 = h4[((size_t)c2 << LOG2C4) + lane];
        float4 v3 = h4[((size_t)c3 << LOG2C4) + lane];
        float a0 = dinv[c0] * dn;
        float a1 = dinv[c1] * dn;
        float a2 = dinv[c2] * dn;
        float a3 = dinv[c3] * dn;
        acc.x += a0 * v0.x + a1 * v1.x + a2 * v2.x + a3 * v3.x;
        acc.y += a0 * v0.y + a1 * v1.y + a2 * v2.y + a3 * v3.y;
        acc.z += a0 * v0.z + a1 * v1.z + a2 * v2.z + a3 * v3.z;
        acc.w += a0 * v0.w + a1 * v1.w + a2 * v2.w + a3 * v3.w;
    }
    for (; i < re; i++) {
        int c = col[i];
        float4 v = h4[((size_t)c << LOG2C4) + lane];
        float w = dinv[c] * dn;
        acc.x += w * v.x; acc.y += w * v.y; acc.z += w * v.z; acc.w += w * v.w;
    }
    if (!ADDIN) {
        acc.x = fmaxf(acc.x, 0.0f); acc.y = fmaxf(acc.y, 0.0f);
        acc.z = fmaxf(acc.z, 0.0f); acc.w = fmaxf(acc.w, 0.0f);
    }
    out4[rowoff] = acc;
}

// ---------------- layer-1 GEMM: [outA|outB] = A @ [WA|WB], K=128, both mats ----------------
__global__ __launch_bounds__(256) void gemm1_k(const float* __restrict__ A,
                                               const float* __restrict__ WA,
                                               const float* __restrict__ WB,
                                               float* __restrict__ outA,
                                               float* __restrict__ outB, int n) {
    __shared__ float As[64 * 68];
    __shared__ float W1s[64 * 68];
    __shared__ float W2s[64 * 68];
    const int t = threadIdx.x;
    const int tj = t & 15;
    const int tn = t >> 4;
    const int n0 = blockIdx.x * 64;
    float acc[4][8] = {};

    for (int kc = 0; kc < 128; kc += 64) {
        if (kc) __syncthreads();
        {
            int idx = t;
#pragma unroll
            for (int r = 0; r < 4; r++, idx += 256) {
                int nl = idx >> 4, q = idx & 15;
                int node = n0 + nl; node = node < n ? node : n - 1;
                float4 a = ((const float4*)A)[(size_t)node * 32 + (kc >> 2) + q];
                *(float4*)&As[nl * 68 + q * 4] = a;
            }
        }
        {
            int idx = t;
#pragma unroll
            for (int r = 0; r < 4; r++, idx += 256) {
                int kl = idx >> 4, j4 = idx & 15;
                *(float4*)&W1s[kl * 68 + j4 * 4] = ((const float4*)WA)[(size_t)(kc + kl) * 16 + j4];
                *(float4*)&W2s[kl * 68 + j4 * 4] = ((const float4*)WB)[(size_t)(kc + kl) * 16 + j4];
            }
        }
        __syncthreads();

        const float* ap = &As[tn * 4 * 68];
        const float* w1p = &W1s[tj * 4];
        const float* w2p = &W2s[tj * 4];
#pragma unroll 2
        for (int k4 = 0; k4 < 16; k4++) {
            float4 a0 = *(const float4*)&ap[0 * 68 + k4 * 4];
            float4 a1 = *(const float4*)&ap[1 * 68 + k4 * 4];
            float4 a2 = *(const float4*)&ap[2 * 68 + k4 * 4];
            float4 a3 = *(const float4*)&ap[3 * 68 + k4 * 4];
#pragma unroll
            for (int kk = 0; kk < 4; kk++) {
                float4 w1 = *(const float4*)&w1p[(k4 * 4 + kk) * 68];
                float4 w2 = *(const float4*)&w2p[(k4 * 4 + kk) * 68];
                float av0 = kk == 0 ? a0.x : kk == 1 ? a0.y : kk == 2 ? a0.z : a0.w;
                float av1 = kk == 0 ? a1.x : kk == 1 ? a1.y : kk == 2 ? a1.z : a1.w;
                float av2 = kk == 0 ? a2.x : kk == 1 ? a2.y : kk == 2 ? a2.z : a2.w;
                float av3 = kk == 0 ? a3.x : kk == 1 ? a3.y : kk == 2 ? a3.z : a3.w;
#define FMA8(m, AV)                                                     \
                acc[m][0] += AV * w1.x; acc[m][1] += AV * w1.y;          \
                acc[m][2] += AV * w1.z; acc[m][3] += AV * w1.w;          \
                acc[m][4] += AV * w2.x; acc[m][5] += AV * w2.y;          \
                acc[m][6] += AV * w2.z; acc[m][7] += AV * w2.w;
                FMA8(0, av0)
                FMA8(1, av1)
                FMA8(2, av2)
                FMA8(3, av3)
#undef FMA8
            }
        }
    }

#pragma unroll
    for (int m = 0; m < 4; m++) {
        int node = n0 + tn * 4 + m;
        if (node < n) {
            *(float4*)&outA[(size_t)node * 64 + tj * 4] =
                make_float4(acc[m][0], acc[m][1], acc[m][2], acc[m][3]);
            *(float4*)&outB[(size_t)node * 64 + tj * 4] =
                make_float4(acc[m][4], acc[m][5], acc[m][6], acc[m][7]);
        }
    }
}

// ---------------- layer-2 GEMM: out = A @ [WA|WB], K=64, JW=32 ----------------
template<int K, int JW>
__global__ __launch_bounds__(256) void gemm_k(const float* __restrict__ A,
                                              const float* __restrict__ WA,
                                              const float* __restrict__ WB,
                                              float* __restrict__ out, int n) {
    __shared__ float As[64 * 68];
    __shared__ float Ws[64 * 68];
    const int t = threadIdx.x;
    const int tj = t & 15;
    const int tn = t >> 4;
    const int n0 = blockIdx.x * 64;
    float acc[4][4] = {};

    for (int kc = 0; kc < K; kc += 64) {
        if (kc) __syncthreads();
        {
            int idx = t;
#pragma unroll
            for (int r = 0; r < 4; r++, idx += 256) {
                int nl = idx >> 4, q = idx & 15;
                int node = n0 + nl; node = node < n ? node : n - 1;
                float4 a = ((const float4*)A)[(size_t)node * (K / 4) + (kc >> 2) + q];
                *(float4*)&As[nl * 68 + q * 4] = a;
            }
        }
        {
            int idx = t;
#pragma unroll
            for (int r = 0; r < 4; r++, idx += 256) {
                int kl = idx >> 4, j4 = idx & 15;
                const float* W = (j4 < 8) ? WA : WB;
                float4 w = ((const float4*)W)[(size_t)(kc + kl) * 8 + (j4 & 7)];
                *(float4*)&Ws[kl * 68 + j4 * 4] = w;
            }
        }
        __syncthreads();

        const float* ap = &As[tn * 4 * 68];
        const float* wp = &Ws[tj * 4];
#pragma unroll 4
        for (int k4 = 0; k4 < 16; k4++) {
            float4 a0 = *(const float4*)&ap[0 * 68 + k4 * 4];
            float4 a1 = *(const float4*)&ap[1 * 68 + k4 * 4];
            float4 a2 = *(const float4*)&ap[2 * 68 + k4 * 4];
            float4 a3 = *(const float4*)&ap[3 * 68 + k4 * 4];
            float4 w0 = *(const float4*)&wp[(k4 * 4 + 0) * 68];
            float4 w1 = *(const float4*)&wp[(k4 * 4 + 1) * 68];
            float4 w2 = *(const float4*)&wp[(k4 * 4 + 2) * 68];
            float4 w3 = *(const float4*)&wp[(k4 * 4 + 3) * 68];
#define FMA_ROW(m, AV)                                                   \
            acc[m][0] += AV.x * w0.x + AV.y * w1.x + AV.z * w2.x + AV.w * w3.x; \
            acc[m][1] += AV.x * w0.y + AV.y * w1.y + AV.z * w2.y + AV.w * w3.y; \
            acc[m][2] += AV.x * w0.z + AV.y * w1.z + AV.z * w2.z + AV.w * w3.z; \
            acc[m][3] += AV.x * w0.w + AV.y * w1.w + AV.z * w2.w + AV.w * w3.w;
            FMA_ROW(0, a0)
            FMA_ROW(1, a1)
            FMA_ROW(2, a2)
            FMA_ROW(3, a3)
#undef FMA_ROW
        }
    }

    int mat = tj >> 3;
    int jw = (tj & 7) * 4;
    float* ob = out + (size_t)mat * n * JW + jw;
#pragma unroll
    for (int m = 0; m < 4; m++) {
        int node = n0 + tn * 4 + m;
        if (node < n)
            *(float4*)&ob[(size_t)node * JW] =
                make_float4(acc[m][0], acc[m][1], acc[m][2], acc[m][3]);
    }
}

// ---------------- fused heads, 8 threads/node ----------------
__global__ __launch_bounds__(256) void heads_k(const float* __restrict__ h2,
                                               const float* __restrict__ Wp1, const float* __restrict__ bp1,
                                               const float* __restrict__ Wp2, const float* __restrict__ bp2,
                                               const float* __restrict__ Wc1, const float* __restrict__ bc1,
                                               const float* __restrict__ Wc2, const float* __restrict__ bc2,
                                               float* __restrict__ coord, float* __restrict__ z, int n) {
    __shared__ float sWp1[32 * 32], sWp2[32 * 32], sWc1[32 * 16], sWc2[32];
    __shared__ float sbp1[32], sbp2[32], sbc1[16], sbc2[2];
    __shared__ float sh[32 * 36], st[32 * 36], stc[32 * 18];
    const int t = threadIdx.x;
    for (int i = t; i < 1024; i += 256) { sWp1[i] = Wp1[i]; sWp2[i] = Wp2[i]; }
    for (int i = t; i < 512; i += 256) sWc1[i] = Wc1[i];
    if (t < 32) { sWc2[t] = Wc2[t]; sbp1[t] = bp1[t]; sbp2[t] = bp2[t]; }
    if (t < 16) sbc1[t] = bc1[t];
    if (t < 2) sbc2[t] = bc2[t];

    const int n0 = blockIdx.x * 32;
    const int nl = t >> 3;
    const int jq = t & 7;
    const int node = n0 + nl;
    {
        float4 v = make_float4(0.f, 0.f, 0.f, 0.f);
        if (node < n) v = *(const float4*)&h2[(size_t)node * 32 + jq * 4];
        *(float4*)&sh[nl * 36 + jq * 4] = v;
    }
    __syncthreads();

    float4 a = *(const float4*)&sbp1[jq * 4];
#pragma unroll
    for (int k = 0; k < 32; k++) {
        float hv = sh[nl * 36 + k];
        float4 w = *(const float4*)&sWp1[k * 32 + jq * 4];
        a.x += hv * w.x; a.y += hv * w.y; a.z += hv * w.z; a.w += hv * w.w;
    }
    a.x = fmaxf(a.x, 0.f); a.y = fmaxf(a.y, 0.f);
    a.z = fmaxf(a.z, 0.f); a.w = fmaxf(a.w, 0.f);
    *(float4*)&st[nl * 36 + jq * 4] = a;

    float2 c = *(const float2*)&sbc1[jq * 2];
#pragma unroll
    for (int k = 0; k < 32; k++) {
        float hv = sh[nl * 36 + k];
        float2 w = *(const float2*)&sWc1[k * 16 + jq * 2];
        c.x += hv * w.x; c.y += hv * w.y;
    }
    c.x = fmaxf(c.x, 0.f); c.y = fmaxf(c.y, 0.f);
    *(float2*)&stc[nl * 18 + jq * 2] = c;
    __syncthreads();

    float4 zz = *(const float4*)&sbp2[jq * 4];
#pragma unroll
    for (int k = 0; k < 32; k++) {
        float tv = st[nl * 36 + k];
        float4 w = *(const float4*)&sWp2[k * 32 + jq * 4];
        zz.x += tv * w.x; zz.y += tv * w.y; zz.z += tv * w.z; zz.w += tv * w.w;
    }
    if (node < n) *(float4*)&z[(size_t)node * 32 + jq * 4] = zz;

    if (jq < 2) {
        float s = sbc2[jq];
#pragma unroll
        for (int k = 0; k < 16; k++) s += stc[nl * 18 + k] * sWc2[k * 2 + jq];
        if (node < n) coord[(size_t)node * 2 + jq] = s;
    }
}

extern "C" void kernel_launch(void* const* d_in, const int* in_sizes, int n_in,
                              void* d_out, int out_size, void* d_ws, size_t ws_size,
                              hipStream_t stream) {
    const float* x    = (const float*)d_in[0];
    const int*   ei   = (const int*)d_in[1];
    const int*   src  = ei;
    const int*   dst  = ei + NE;
    const float* W1_1 = (const float*)d_in[2];
    const float* W1_2 = (const float*)d_in[3];
    const float* b1   = (const float*)d_in[4];
    const float* W2_1 = (const float*)d_in[5];
    const float* W2_2 = (const float*)d_in[6];
    const float* b2   = (const float*)d_in[7];
    const float* Wp1  = (const float*)d_in[8];
    const float* bp1  = (const float*)d_in[9];
    const float* Wp2  = (const float*)d_in[10];
    const float* bp2  = (const float*)d_in[11];
    const float* Wc1  = (const float*)d_in[12];
    const float* bc1  = (const float*)d_in[13];
    const float* Wc2  = (const float*)d_in[14];
    const float* bc2  = (const float*)d_in[15];

    // workspace layout (word offsets tuned so bufY is 16B-aligned:
    // 50000+50000+50004+256+800000+800000 = 1750260 words, %4 == 0)
    float* ws    = (float*)d_ws;
    float* dinv  = ws;                              // NN
    int*   cnt   = (int*)(dinv + NN);               // NN
    int*   rows  = cnt + NN;                        // NN+4 (padded)
    int*   bsum  = rows + NN + 4;                   // 256
    int*   rank  = bsum + 256;                      // NE
    int*   col   = rank + NE;                       // NE
    float* bufY  = (float*)(col + NE);              // NN*128 (16B aligned)
    float* bufZ  = bufY + (size_t)NN * 128;         // NN*64

    float* y1 = bufY;                       // NN*64   (then reused as u)
    float* y2 = bufY + (size_t)NN * 64;     // NN*64   (then reused as h1)
    float* u  = y1;
    float* h1 = y2;
    float* z1 = bufZ;                       // NN*32   (then reused as u2)
    float* z2 = bufZ + (size_t)NN * 32;     // NN*32   (then reused as h2)
    float* u2 = z1;
    float* h2 = z2;

    float* coord = (float*)d_out;                   // NN*2
    float* z     = (float*)d_out + 2 * NN;          // NN*32

    // 1) CSR build + dinv (rank captured in hist; scatter atomic-free)
    zero_cnt_k<<<(NN + 255) / 256, 256, 0, stream>>>(cnt);
    hist_k<<<(NE + 255) / 256, 256, 0, stream>>>(dst, cnt, rank);
    sum_blocks_k<<<NBLK, 256, 0, stream>>>(cnt, bsum, dinv);
    scan_blocks_k<<<1, 256, 0, stream>>>(bsum, rows);
    scan_final_k<<<NBLK, 256, 0, stream>>>(cnt, bsum, rows);
    scatter_k<<<(NE + 255) / 256, 256, 0, stream>>>(src, dst, rank, rows, col);

    // 2) [y1|y2] = x @ [W1_1|W1_2]   (K=128, both matrices in one pass)
    gemm1_k<<<(NN + 63) / 64, 256, 0, stream>>>(x, W1_1, W1_2, y1, y2, NN);
    // 3) u = y1 + P(y2)              (C=64)
    prop_k<4, true><<<(NN * 16 + 255) / 256, 256, 0, stream>>>(
        (const float4*)y2, (const float4*)y1, nullptr, (float4*)u, rows, col, dinv);
    // 4) h1 = relu(P(u) + b1)        (C=64)
    prop_k<4, false><<<(NN * 16 + 255) / 256, 256, 0, stream>>>(
        (const float4*)u, nullptr, b1, (float4*)h1, rows, col, dinv);
    // 5) [z1|z2] = h1 @ [W2_1|W2_2]  (K=64, one block spans both 32-wide mats)
    gemm_k<64, 32><<<(NN + 63) / 64, 256, 0, stream>>>(h1, W2_1, W2_2, bufZ, NN);
    // 6) u2 = z1 + P(z2)             (C=32)
    prop_k<3, true><<<(NN * 8 + 255) / 256, 256, 0, stream>>>(
        (const float4*)z2, (const float4*)z1, nullptr, (float4*)u2, rows, col, dinv);
    // 7) h2 = relu(P(u2) + b2)       (C=32)
    prop_k<3, false><<<(NN * 8 + 255) / 256, 256, 0, stream>>>(
        (const float4*)u2, nullptr, b2, (float4*)h2, rows, col, dinv);
    // 8) heads (8 threads/node)
    heads_k<<<(NN + 31) / 32, 256, 0, stream>>>(h2, Wp1, bp1, Wp2, bp2, Wc1, bc1, Wc2, bc2, coord, z, NN);
}

// Round 10
// 329.258 us; speedup vs baseline: 1.1451x; 1.0005x over previous
//
#include <hip/hip_runtime.h>

#define NN 50000
#define NE 800000
#define NBLK ((NN + 255) / 256)   // 196 scan blocks

// ---------------- CSR build ----------------
__global__ __launch_bounds__(256) void zero_cnt_k(int* __restrict__ cnt) {
    int i = blockIdx.x * blockDim.x + threadIdx.x;
    if (i < NN) cnt[i] = 0;
}

// histogram + per-edge rank within its dst row (atomic return value)
__global__ __launch_bounds__(256) void hist_k(const int* __restrict__ dst,
                                              int* __restrict__ cnt,
                                              int* __restrict__ rank) {
    int e = blockIdx.x * blockDim.x + threadIdx.x;
    if (e < NE) rank[e] = atomicAdd(&cnt[dst[e]], 1);
}

// ---- hierarchical scan: cnt -> rowstart (exclusive) ----
// phase 1: per-block sums; also computes dinv = rsqrt(deg+1)
__global__ __launch_bounds__(256) void sum_blocks_k(const int* __restrict__ cnt,
                                                    int* __restrict__ bsum,
                                                    float* __restrict__ dinv) {
    __shared__ int s[256];
    int t = threadIdx.x;
    int i = blockIdx.x * 256 + t;
    int v = (i < NN) ? cnt[i] : 0;
    s[t] = v;
    if (i < NN) dinv[i] = rsqrtf((float)(v + 1));  // +1 self loop
    __syncthreads();
    for (int off = 128; off > 0; off >>= 1) {
        if (t < off) s[t] += s[t + off];
        __syncthreads();
    }
    if (t == 0) bsum[blockIdx.x] = s[0];
}

// phase 2: exclusive scan of NBLK block sums (single tiny block), plus tail
__global__ __launch_bounds__(256) void scan_blocks_k(int* __restrict__ bsum,
                                                     int* __restrict__ rowstart) {
    __shared__ int s[256];
    int t = threadIdx.x;
    int v = (t < NBLK) ? bsum[t] : 0;
    s[t] = v;
    __syncthreads();
    for (int off = 1; off < 256; off <<= 1) {
        int x = (t >= off) ? s[t - off] : 0;
        __syncthreads();
        s[t] += x;
        __syncthreads();
    }
    if (t < NBLK) bsum[t] = s[t] - v;  // exclusive
    if (t == 0) rowstart[NN] = NE;
}

// phase 3: per-block exclusive scan + block offset
__global__ __launch_bounds__(256) void scan_final_k(const int* __restrict__ cnt,
                                                    const int* __restrict__ bsum,
                                                    int* __restrict__ rowstart) {
    __shared__ int s[256];
    int t = threadIdx.x;
    int i = blockIdx.x * 256 + t;
    int v = (i < NN) ? cnt[i] : 0;
    s[t] = v;
    __syncthreads();
    for (int off = 1; off < 256; off <<= 1) {
        int x = (t >= off) ? s[t - off] : 0;
        __syncthreads();
        s[t] += x;
        __syncthreads();
    }
    if (i < NN) rowstart[i] = bsum[blockIdx.x] + s[t] - v;  // exclusive
}

// atomic-free scatter: position known from rowstart + precomputed rank
__global__ __launch_bounds__(256) void scatter_k(const int* __restrict__ src,
                                                 const int* __restrict__ dst,
                                                 const int* __restrict__ rank,
                                                 const int* __restrict__ rowstart,
                                                 int* __restrict__ col) {
    int e = blockIdx.x * blockDim.x + threadIdx.x;
    if (e >= NE) return;
    col[rowstart[dst[e]] + rank[e]] = src[e];
}

// ---------------- propagation (CSR, dst-stationary) ----------------
// weight computed inline: w = dinv[col] * dinv[node] (bit-identical to packed).
// 8-wide edge unroll: 8 independent 256B row gathers in flight per thread
// (latency-bound regime: col ~200cyc L2 + row ~600cyc LLC; deeper MLP covers it).
template<int LOG2C4, bool ADDIN>
__global__ __launch_bounds__(256) void prop_k(const float4* __restrict__ h4,
                                              const float4* __restrict__ addin4,
                                              const float* __restrict__ bias,
                                              float4* __restrict__ out4,
                                              const int* __restrict__ rowstart,
                                              const int* __restrict__ col,
                                              const float* __restrict__ dinv) {
    const int C4 = 1 << LOG2C4;
    unsigned tid = blockIdx.x * blockDim.x + threadIdx.x;
    unsigned node = tid >> LOG2C4;
    if (node >= NN) return;
    unsigned lane = tid & (C4 - 1);
    size_t rowoff = ((size_t)node << LOG2C4) + lane;
    float dn = dinv[node];
    float w0 = dn * dn;
    float4 hv = h4[rowoff];
    float4 acc;
    if (ADDIN) {
        float4 a = addin4[rowoff];
        acc.x = a.x + w0 * hv.x; acc.y = a.y + w0 * hv.y;
        acc.z = a.z + w0 * hv.z; acc.w = a.w + w0 * hv.w;
    } else {
        float4 b = ((const float4*)bias)[lane];
        acc.x = b.x + w0 * hv.x; acc.y = b.y + w0 * hv.y;
        acc.z = b.z + w0 * hv.z; acc.w = b.w + w0 * hv.w;
    }
    int rs = rowstart[node], re = rowstart[node + 1];
    int i = rs;
    for (; i + 8 <= re; i += 8) {
        int c0 = col[i + 0];
        int c1 = col[i + 1];
        int c2 = col[i + 2];
        int c3 = col[i + 3];
        int c4 = col[i + 4];
        int c5 = col[i + 5];
        int c6 = col[i + 6];
        int c7 = col[i + 7];
        float4 v0 = h4[((size_t)c0 << LOG2C4) + lane];
        float4 v1 = h4[((size_t)c1 << LOG2C4) + lane];
        float4 v2 = h4[((size_t)c2 << LOG2C4) + lane];
        float4 v3 = h4[((size_t)c3 << LOG2C4) + lane];
        float4 v4 = h4[((size_t)c4 << LOG2C4) + lane];
        float4 v5 = h4[((size_t)c5 << LOG2C4) + lane];
        float4 v6 = h4[((size_t)c6 << LOG2C4) + lane];
        float4 v7 = h4[((size_t)c7 << LOG2C4) + lane];
        float a0 = dinv[c0] * dn;
        float a1 = dinv[c1] * dn;
        float a2 = dinv[c2] * dn;
        float a3 = dinv[c3] * dn;
        float a4 = dinv[c4] * dn;
        float a5 = dinv[c5] * dn;
        float a6 = dinv[c6] * dn;
        float a7 = dinv[c7] * dn;
        acc.x += a0 * v0.x + a1 * v1.x + a2 * v2.x + a3 * v3.x
               + a4 * v4.x + a5 * v5.x + a6 * v6.x + a7 * v7.x;
        acc.y += a0 * v0.y + a1 * v1.y + a2 * v2.y + a3 * v3.y
               + a4 * v4.y + a5 * v5.y + a6 * v6.y + a7 * v7.y;
        acc.z += a0 * v0.z + a1 * v1.z + a2 * v2.z + a3 * v3.z
               + a4 * v4.z + a5 * v5.z + a6 * v6.z + a7 * v7.z;
        acc.w += a0 * v0.w + a1 * v1.w + a2 * v2.w + a3 * v3.w
               + a4 * v4.w + a5 * v5.w + a6 * v6.w + a7 * v7.w;
    }
    for (; i + 4 <= re; i += 4) {
        int c0 = col[i + 0];
        int c1 = col[i + 1];
        int c2 = col[i + 2];
        int c3 = col[i + 3];
        float4 v0 = h4[((size_t)c0 << LOG2C4) + lane];
        float4 v1 = h4[((size_t)c1 << LOG2C4) + lane];
        float4 v2 = h4[((size_t)c2 << LOG2C4) + lane];
        float4 v3 = h4[((size_t)c3 << LOG2C4) + lane];
        float a0 = dinv[c0] * dn;
        float a1 = dinv[c1] * dn;
        float a2 = dinv[c2] * dn;
        float a3 = dinv[c3] * dn;
        acc.x += a0 * v0.x + a1 * v1.x + a2 * v2.x + a3 * v3.x;
        acc.y += a0 * v0.y + a1 * v1.y + a2 * v2.y + a3 * v3.y;
        acc.z += a0 * v0.z + a1 * v1.z + a2 * v2.z + a3 * v3.z;
        acc.w += a0 * v0.w + a1 * v1.w + a2 * v2.w + a3 * v3.w;
    }
    for (; i < re; i++) {
        int c = col[i];
        float4 v = h4[((size_t)c << LOG2C4) + lane];
        float w = dinv[c] * dn;
        acc.x += w * v.x; acc.y += w * v.y; acc.z += w * v.z; acc.w += w * v.w;
    }
    if (!ADDIN) {
        acc.x = fmaxf(acc.x, 0.0f); acc.y = fmaxf(acc.y, 0.0f);
        acc.z = fmaxf(acc.z, 0.0f); acc.w = fmaxf(acc.w, 0.0f);
    }
    out4[rowoff] = acc;
}

// ---------------- layer-1 GEMM: [outA|outB] = A @ [WA|WB], K=128, both mats ----------------
__global__ __launch_bounds__(256) void gemm1_k(const float* __restrict__ A,
                                               const float* __restrict__ WA,
                                               const float* __restrict__ WB,
                                               float* __restrict__ outA,
                                               float* __restrict__ outB, int n) {
    __shared__ float As[64 * 68];
    __shared__ float W1s[64 * 68];
    __shared__ float W2s[64 * 68];
    const int t = threadIdx.x;
    const int tj = t & 15;
    const int tn = t >> 4;
    const int n0 = blockIdx.x * 64;
    float acc[4][8] = {};

    for (int kc = 0; kc < 128; kc += 64) {
        if (kc) __syncthreads();
        {
            int idx = t;
#pragma unroll
            for (int r = 0; r < 4; r++, idx += 256) {
                int nl = idx >> 4, q = idx & 15;
                int node = n0 + nl; node = node < n ? node : n - 1;
                float4 a = ((const float4*)A)[(size_t)node * 32 + (kc >> 2) + q];
                *(float4*)&As[nl * 68 + q * 4] = a;
            }
        }
        {
            int idx = t;
#pragma unroll
            for (int r = 0; r < 4; r++, idx += 256) {
                int kl = idx >> 4, j4 = idx & 15;
                *(float4*)&W1s[kl * 68 + j4 * 4] = ((const float4*)WA)[(size_t)(kc + kl) * 16 + j4];
                *(float4*)&W2s[kl * 68 + j4 * 4] = ((const float4*)WB)[(size_t)(kc + kl) * 16 + j4];
            }
        }
        __syncthreads();

        const float* ap = &As[tn * 4 * 68];
        const float* w1p = &W1s[tj * 4];
        const float* w2p = &W2s[tj * 4];
#pragma unroll 2
        for (int k4 = 0; k4 < 16; k4++) {
            float4 a0 = *(const float4*)&ap[0 * 68 + k4 * 4];
            float4 a1 = *(const float4*)&ap[1 * 68 + k4 * 4];
            float4 a2 = *(const float4*)&ap[2 * 68 + k4 * 4];
            float4 a3 = *(const float4*)&ap[3 * 68 + k4 * 4];
#pragma unroll
            for (int kk = 0; kk < 4; kk++) {
                float4 w1 = *(const float4*)&w1p[(k4 * 4 + kk) * 68];
                float4 w2 = *(const float4*)&w2p[(k4 * 4 + kk) * 68];
                float av0 = kk == 0 ? a0.x : kk == 1 ? a0.y : kk == 2 ? a0.z : a0.w;
                float av1 = kk == 0 ? a1.x : kk == 1 ? a1.y : kk == 2 ? a1.z : a1.w;
                float av2 = kk == 0 ? a2.x : kk == 1 ? a2.y : kk == 2 ? a2.z : a2.w;
                float av3 = kk == 0 ? a3.x : kk == 1 ? a3.y : kk == 2 ? a3.z : a3.w;
#define FMA8(m, AV)                                                     \
                acc[m][0] += AV * w1.x; acc[m][1] += AV * w1.y;          \
                acc[m][2] += AV * w1.z; acc[m][3] += AV * w1.w;          \
                acc[m][4] += AV * w2.x; acc[m][5] += AV * w2.y;          \
                acc[m][6] += AV * w2.z; acc[m][7] += AV * w2.w;
                FMA8(0, av0)
                FMA8(1, av1)
                FMA8(2, av2)
                FMA8(3, av3)
#undef FMA8
            }
        }
    }

#pragma unroll
    for (int m = 0; m < 4; m++) {
        int node = n0 + tn * 4 + m;
        if (node < n) {
            *(float4*)&outA[(size_t)node * 64 + tj * 4] =
                make_float4(acc[m][0], acc[m][1], acc[m][2], acc[m][3]);
            *(float4*)&outB[(size_t)node * 64 + tj * 4] =
                make_float4(acc[m][4], acc[m][5], acc[m][6], acc[m][7]);
        }
    }
}

// ---------------- layer-2 GEMM: out = A @ [WA|WB], K=64, JW=32 ----------------
template<int K, int JW>
__global__ __launch_bounds__(256) void gemm_k(const float* __restrict__ A,
                                              const float* __restrict__ WA,
                                              const float* __restrict__ WB,
                                              float* __restrict__ out, int n) {
    __shared__ float As[64 * 68];
    __shared__ float Ws[64 * 68];
    const int t = threadIdx.x;
    const int tj = t & 15;
    const int tn = t >> 4;
    const int n0 = blockIdx.x * 64;
    float acc[4][4] = {};

    for (int kc = 0; kc < K; kc += 64) {
        if (kc) __syncthreads();
        {
            int idx = t;
#pragma unroll
            for (int r = 0; r < 4; r++, idx += 256) {
                int nl = idx >> 4, q = idx & 15;
                int node = n0 + nl; node = node < n ? node : n - 1;
                float4 a = ((const float4*)A)[(size_t)node * (K / 4) + (kc >> 2) + q];
                *(float4*)&As[nl * 68 + q * 4] = a;
            }
        }
        {
            int idx = t;
#pragma unroll
            for (int r = 0; r < 4; r++, idx += 256) {
                int kl = idx >> 4, j4 = idx & 15;
                const float* W = (j4 < 8) ? WA : WB;
                float4 w = ((const float4*)W)[(size_t)(kc + kl) * 8 + (j4 & 7)];
                *(float4*)&Ws[kl * 68 + j4 * 4] = w;
            }
        }
        __syncthreads();

        const float* ap = &As[tn * 4 * 68];
        const float* wp = &Ws[tj * 4];
#pragma unroll 4
        for (int k4 = 0; k4 < 16; k4++) {
            float4 a0 = *(const float4*)&ap[0 * 68 + k4 * 4];
            float4 a1 = *(const float4*)&ap[1 * 68 + k4 * 4];
            float4 a2 = *(const float4*)&ap[2 * 68 + k4 * 4];
            float4 a3 = *(const float4*)&ap[3 * 68 + k4 * 4];
            float4 w0 = *(const float4*)&wp[(k4 * 4 + 0) * 68];
            float4 w1 = *(const float4*)&wp[(k4 * 4 + 1) * 68];
            float4 w2 = *(const float4*)&wp[(k4 * 4 + 2) * 68];
            float4 w3 = *(const float4*)&wp[(k4 * 4 + 3) * 68];
#define FMA_ROW(m, AV)                                                   \
            acc[m][0] += AV.x * w0.x + AV.y * w1.x + AV.z * w2.x + AV.w * w3.x; \
            acc[m][1] += AV.x * w0.y + AV.y * w1.y + AV.z * w2.y + AV.w * w3.y; \
            acc[m][2] += AV.x * w0.z + AV.y * w1.z + AV.z * w2.z + AV.w * w3.z; \
            acc[m][3] += AV.x * w0.w + AV.y * w1.w + AV.z * w2.w + AV.w * w3.w;
            FMA_ROW(0, a0)
            FMA_ROW(1, a1)
            FMA_ROW(2, a2)
            FMA_ROW(3, a3)
#undef FMA_ROW
        }
    }

    int mat = tj >> 3;
    int jw = (tj & 7) * 4;
    float* ob = out + (size_t)mat * n * JW + jw;
#pragma unroll
    for (int m = 0; m < 4; m++) {
        int node = n0 + tn * 4 + m;
        if (node < n)
            *(float4*)&ob[(size_t)node * JW] =
                make_float4(acc[m][0], acc[m][1], acc[m][2], acc[m][3]);
    }
}

// ---------------- fused heads, 8 threads/node ----------------
__global__ __launch_bounds__(256) void heads_k(const float* __restrict__ h2,
                                               const float* __restrict__ Wp1, const float* __restrict__ bp1,
                                               const float* __restrict__ Wp2, const float* __restrict__ bp2,
                                               const float* __restrict__ Wc1, const float* __restrict__ bc1,
                                               const float* __restrict__ Wc2, const float* __restrict__ bc2,
                                               float* __restrict__ coord, float* __restrict__ z, int n) {
    __shared__ float sWp1[32 * 32], sWp2[32 * 32], sWc1[32 * 16], sWc2[32];
    __shared__ float sbp1[32], sbp2[32], sbc1[16], sbc2[2];
    __shared__ float sh[32 * 36], st[32 * 36], stc[32 * 18];
    const int t = threadIdx.x;
    for (int i = t; i < 1024; i += 256) { sWp1[i] = Wp1[i]; sWp2[i] = Wp2[i]; }
    for (int i = t; i < 512; i += 256) sWc1[i] = Wc1[i];
    if (t < 32) { sWc2[t] = Wc2[t]; sbp1[t] = bp1[t]; sbp2[t] = bp2[t]; }
    if (t < 16) sbc1[t] = bc1[t];
    if (t < 2) sbc2[t] = bc2[t];

    const int n0 = blockIdx.x * 32;
    const int nl = t >> 3;
    const int jq = t & 7;
    const int node = n0 + nl;
    {
        float4 v = make_float4(0.f, 0.f, 0.f, 0.f);
        if (node < n) v = *(const float4*)&h2[(size_t)node * 32 + jq * 4];
        *(float4*)&sh[nl * 36 + jq * 4] = v;
    }
    __syncthreads();

    float4 a = *(const float4*)&sbp1[jq * 4];
#pragma unroll
    for (int k = 0; k < 32; k++) {
        float hv = sh[nl * 36 + k];
        float4 w = *(const float4*)&sWp1[k * 32 + jq * 4];
        a.x += hv * w.x; a.y += hv * w.y; a.z += hv * w.z; a.w += hv * w.w;
    }
    a.x = fmaxf(a.x, 0.f); a.y = fmaxf(a.y, 0.f);
    a.z = fmaxf(a.z, 0.f); a.w = fmaxf(a.w, 0.f);
    *(float4*)&st[nl * 36 + jq * 4] = a;

    float2 c = *(const float2*)&sbc1[jq * 2];
#pragma unroll
    for (int k = 0; k < 32; k++) {
        float hv = sh[nl * 36 + k];
        float2 w = *(const float2*)&sWc1[k * 16 + jq * 2];
        c.x += hv * w.x; c.y += hv * w.y;
    }
    c.x = fmaxf(c.x, 0.f); c.y = fmaxf(c.y, 0.f);
    *(float2*)&stc[nl * 18 + jq * 2] = c;
    __syncthreads();

    float4 zz = *(const float4*)&sbp2[jq * 4];
#pragma unroll
    for (int k = 0; k < 32; k++) {
        float tv = st[nl * 36 + k];
        float4 w = *(const float4*)&sWp2[k * 32 + jq * 4];
        zz.x += tv * w.x; zz.y += tv * w.y; zz.z += tv * w.z; zz.w += tv * w.w;
    }
    if (node < n) *(float4*)&z[(size_t)node * 32 + jq * 4] = zz;

    if (jq < 2) {
        float s = sbc2[jq];
#pragma unroll
        for (int k = 0; k < 16; k++) s += stc[nl * 18 + k] * sWc2[k * 2 + jq];
        if (node < n) coord[(size_t)node * 2 + jq] = s;
    }
}

extern "C" void kernel_launch(void* const* d_in, const int* in_sizes, int n_in,
                              void* d_out, int out_size, void* d_ws, size_t ws_size,
                              hipStream_t stream) {
    const float* x    = (const float*)d_in[0];
    const int*   ei   = (const int*)d_in[1];
    const int*   src  = ei;
    const int*   dst  = ei + NE;
    const float* W1_1 = (const float*)d_in[2];
    const float* W1_2 = (const float*)d_in[3];
    const float* b1   = (const float*)d_in[4];
    const float* W2_1 = (const float*)d_in[5];
    const float* W2_2 = (const float*)d_in[6];
    const float* b2   = (const float*)d_in[7];
    const float* Wp1  = (const float*)d_in[8];
    const float* bp1  = (const float*)d_in[9];
    const float* Wp2  = (const float*)d_in[10];
    const float* bp2  = (const float*)d_in[11];
    const float* Wc1  = (const float*)d_in[12];
    const float* bc1  = (const float*)d_in[13];
    const float* Wc2  = (const float*)d_in[14];
    const float* bc2  = (const float*)d_in[15];

    // workspace layout (word offsets: 50000+50000+50004+256+800000+800000
    // = 1750260 words, %4 == 0 -> bufY 16B aligned)
    float* ws    = (float*)d_ws;
    float* dinv  = ws;                              // NN
    int*   cnt   = (int*)(dinv + NN);               // NN
    int*   rows  = cnt + NN;                        // NN+4 (padded)
    int*   bsum  = rows + NN + 4;                   // 256
    int*   rank  = bsum + 256;                      // NE
    int*   col   = rank + NE;                       // NE
    float* bufY  = (float*)(col + NE);              // NN*128 (16B aligned)
    float* bufZ  = bufY + (size_t)NN * 128;         // NN*64

    float* y1 = bufY;                       // NN*64   (then reused as u)
    float* y2 = bufY + (size_t)NN * 64;     // NN*64   (then reused as h1)
    float* u  = y1;
    float* h1 = y2;
    float* z1 = bufZ;                       // NN*32   (then reused as u2)
    float* z2 = bufZ + (size_t)NN * 32;     // NN*32   (then reused as h2)
    float* u2 = z1;
    float* h2 = z2;

    float* coord = (float*)d_out;                   // NN*2
    float* z     = (float*)d_out + 2 * NN;          // NN*32

    // 1) CSR build + dinv (rank captured in hist; scatter atomic-free)
    zero_cnt_k<<<(NN + 255) / 256, 256, 0, stream>>>(cnt);
    hist_k<<<(NE + 255) / 256, 256, 0, stream>>>(dst, cnt, rank);
    sum_blocks_k<<<NBLK, 256, 0, stream>>>(cnt, bsum, dinv);
    scan_blocks_k<<<1, 256, 0, stream>>>(bsum, rows);
    scan_final_k<<<NBLK, 256, 0, stream>>>(cnt, bsum, rows);
    scatter_k<<<(NE + 255) / 256, 256, 0, stream>>>(src, dst, rank, rows, col);

    // 2) [y1|y2] = x @ [W1_1|W1_2]   (K=128, both matrices in one pass)
    gemm1_k<<<(NN + 63) / 64, 256, 0, stream>>>(x, W1_1, W1_2, y1, y2, NN);
    // 3) u = y1 + P(y2)              (C=64)
    prop_k<4, true><<<(NN * 16 + 255) / 256, 256, 0, stream>>>(
        (const float4*)y2, (const float4*)y1, nullptr, (float4*)u, rows, col, dinv);
    // 4) h1 = relu(P(u) + b1)        (C=64)
    prop_k<4, false><<<(NN * 16 + 255) / 256, 256, 0, stream>>>(
        (const float4*)u, nullptr, b1, (float4*)h1, rows, col, dinv);
    // 5) [z1|z2] = h1 @ [W2_1|W2_2]  (K=64, one block spans both 32-wide mats)
    gemm_k<64, 32><<<(NN + 63) / 64, 256, 0, stream>>>(h1, W2_1, W2_2, bufZ, NN);
    // 6) u2 = z1 + P(z2)             (C=32)
    prop_k<3, true><<<(NN * 8 + 255) / 256, 256, 0, stream>>>(
        (const float4*)z2, (const float4*)z1, nullptr, (float4*)u2, rows, col, dinv);
    // 7) h2 = relu(P(u2) + b2)       (C=32)
    prop_k<3, false><<<(NN * 8 + 255) / 256, 256, 0, stream>>>(
        (const float4*)u2, nullptr, b2, (float4*)h2, rows, col, dinv);
    // 8) heads (8 threads/node)
    heads_k<<<(NN + 31) / 32, 256, 0, stream>>>(h2, Wp1, bp1, Wp2, bp2, Wc1, bc1, Wc2, bc2, coord, z, NN);
}

// Round 11
// 317.576 us; speedup vs baseline: 1.1872x; 1.0368x over previous
//
#include <hip/hip_runtime.h>

#define NN 50000
#define NE 800000
#define S 4                         // src bins per row (L2-resident gather slices)
#define BINW 12500                  // NN / S exactly
#define NN4 (NN * S)                // 200000 split-CSR buckets
#define NBLK2 ((NN4 + 255) / 256)   // 782 scan blocks

// ---------------- split-CSR build ----------------
__global__ __launch_bounds__(256) void zero_cnt_k(int* __restrict__ cnt) {
    int i = blockIdx.x * blockDim.x + threadIdx.x;
    if (i < NN4) cnt[i] = 0;
}

// bucket histogram + per-edge rank within its (dst, srcbin) bucket
__global__ __launch_bounds__(256) void hist_k(const int* __restrict__ src,
                                              const int* __restrict__ dst,
                                              int* __restrict__ cnt,
                                              int* __restrict__ rank) {
    int e = blockIdx.x * blockDim.x + threadIdx.x;
    if (e >= NE) return;
    int s = src[e], d = dst[e];
    int b = s / BINW;
    rank[e] = atomicAdd(&cnt[d * S + b], 1);
}

// ---- hierarchical scan over NN4 buckets: cnt -> rowsS (exclusive) ----
// phase 1: per-block sums; also dinv = rsqrt(deg+1), deg = sum of node's 4 bins
__global__ __launch_bounds__(256) void sum_blocks_k(const int* __restrict__ cnt,
                                                    int* __restrict__ bsum,
                                                    float* __restrict__ dinv) {
    __shared__ int s[256];
    int t = threadIdx.x;
    int i = blockIdx.x * 256 + t;
    int v = (i < NN4) ? cnt[i] : 0;
    s[t] = v;
    if (i < NN4 && (i & 3) == 0) {
        int deg = cnt[i] + cnt[i + 1] + cnt[i + 2] + cnt[i + 3];
        dinv[i >> 2] = rsqrtf((float)(deg + 1));  // +1 self loop
    }
    __syncthreads();
    for (int off = 128; off > 0; off >>= 1) {
        if (t < off) s[t] += s[t + off];
        __syncthreads();
    }
    if (t == 0) bsum[blockIdx.x] = s[0];
}

// phase 2: exclusive scan of NBLK2 (=782) block sums in one 1024-thread block
__global__ __launch_bounds__(1024) void scan_blocks_k(int* __restrict__ bsum,
                                                      int* __restrict__ rowsS) {
    __shared__ int s[1024];
    int t = threadIdx.x;
    int v = (t < NBLK2) ? bsum[t] : 0;
    s[t] = v;
    __syncthreads();
    for (int off = 1; off < 1024; off <<= 1) {
        int x = (t >= off) ? s[t - off] : 0;
        __syncthreads();
        s[t] += x;
        __syncthreads();
    }
    if (t < NBLK2) bsum[t] = s[t] - v;  // exclusive
    if (t == 0) rowsS[NN4] = NE;
}

// phase 3: per-block exclusive scan + block offset
__global__ __launch_bounds__(256) void scan_final_k(const int* __restrict__ cnt,
                                                    const int* __restrict__ bsum,
                                                    int* __restrict__ rowsS) {
    __shared__ int s[256];
    int t = threadIdx.x;
    int i = blockIdx.x * 256 + t;
    int v = (i < NN4) ? cnt[i] : 0;
    s[t] = v;
    __syncthreads();
    for (int off = 1; off < 256; off <<= 1) {
        int x = (t >= off) ? s[t - off] : 0;
        __syncthreads();
        s[t] += x;
        __syncthreads();
    }
    if (i < NN4) rowsS[i] = bsum[blockIdx.x] + s[t] - v;  // exclusive
}

// atomic-free scatter into (dst, srcbin)-ordered col
__global__ __launch_bounds__(256) void scatter_k(const int* __restrict__ src,
                                                 const int* __restrict__ dst,
                                                 const int* __restrict__ rank,
                                                 const int* __restrict__ rowsS,
                                                 int* __restrict__ col) {
    int e = blockIdx.x * blockDim.x + threadIdx.x;
    if (e >= NE) return;
    int s = src[e], d = dst[e];
    int b = s / BINW;
    col[rowsS[d * S + b] + rank[e]] = s;
}

// ---------------- propagation (split-CSR, dst-stationary) ----------------
// Per-bin sub-loops: waves reconverge at bin boundaries, so resident blocks'
// gathers concentrate on one ~NN/S-row source slice at a time (L2-resident).
// weight inline: w = dinv[col] * dinv[node].
template<int LOG2C4, bool ADDIN>
__global__ __launch_bounds__(256) void prop_k(const float4* __restrict__ h4,
                                              const float4* __restrict__ addin4,
                                              const float* __restrict__ bias,
                                              float4* __restrict__ out4,
                                              const int* __restrict__ rowsS,
                                              const int* __restrict__ col,
                                              const float* __restrict__ dinv) {
    const int C4 = 1 << LOG2C4;
    unsigned tid = blockIdx.x * blockDim.x + threadIdx.x;
    unsigned node = tid >> LOG2C4;
    if (node >= NN) return;
    unsigned lane = tid & (C4 - 1);
    size_t rowoff = ((size_t)node << LOG2C4) + lane;
    float dn = dinv[node];
    float w0 = dn * dn;
    float4 hv = h4[rowoff];
    float4 acc;
    if (ADDIN) {
        float4 a = addin4[rowoff];
        acc.x = a.x + w0 * hv.x; acc.y = a.y + w0 * hv.y;
        acc.z = a.z + w0 * hv.z; acc.w = a.w + w0 * hv.w;
    } else {
        float4 b = ((const float4*)bias)[lane];
        acc.x = b.x + w0 * hv.x; acc.y = b.y + w0 * hv.y;
        acc.z = b.z + w0 * hv.z; acc.w = b.w + w0 * hv.w;
    }
    int base = node * S;
    int rs = rowsS[base];
#pragma unroll
    for (int p = 1; p <= S; p++) {
        int re = rowsS[base + p];
        int i = rs;
        for (; i + 4 <= re; i += 4) {
            int c0 = col[i + 0];
            int c1 = col[i + 1];
            int c2 = col[i + 2];
            int c3 = col[i + 3];
            float4 v0 = h4[((size_t)c0 << LOG2C4) + lane];
            float4 v1 = h4[((size_t)c1 << LOG2C4) + lane];
            float4 v2 = h4[((size_t)c2 << LOG2C4) + lane];
            float4 v3 = h4[((size_t)c3 << LOG2C4) + lane];
            float a0 = dinv[c0] * dn;
            float a1 = dinv[c1] * dn;
            float a2 = dinv[c2] * dn;
            float a3 = dinv[c3] * dn;
            acc.x += a0 * v0.x + a1 * v1.x + a2 * v2.x + a3 * v3.x;
            acc.y += a0 * v0.y + a1 * v1.y + a2 * v2.y + a3 * v3.y;
            acc.z += a0 * v0.z + a1 * v1.z + a2 * v2.z + a3 * v3.z;
            acc.w += a0 * v0.w + a1 * v1.w + a2 * v2.w + a3 * v3.w;
        }
        for (; i < re; i++) {
            int c = col[i];
            float4 v = h4[((size_t)c << LOG2C4) + lane];
            float w = dinv[c] * dn;
            acc.x += w * v.x; acc.y += w * v.y; acc.z += w * v.z; acc.w += w * v.w;
        }
        rs = re;
    }
    if (!ADDIN) {
        acc.x = fmaxf(acc.x, 0.0f); acc.y = fmaxf(acc.y, 0.0f);
        acc.z = fmaxf(acc.z, 0.0f); acc.w = fmaxf(acc.w, 0.0f);
    }
    out4[rowoff] = acc;
}

// ---------------- layer-1 GEMM: [outA|outB] = A @ [WA|WB], K=128, both mats ----------------
__global__ __launch_bounds__(256) void gemm1_k(const float* __restrict__ A,
                                               const float* __restrict__ WA,
                                               const float* __restrict__ WB,
                                               float* __restrict__ outA,
                                               float* __restrict__ outB, int n) {
    __shared__ float As[64 * 68];
    __shared__ float W1s[64 * 68];
    __shared__ float W2s[64 * 68];
    const int t = threadIdx.x;
    const int tj = t & 15;
    const int tn = t >> 4;
    const int n0 = blockIdx.x * 64;
    float acc[4][8] = {};

    for (int kc = 0; kc < 128; kc += 64) {
        if (kc) __syncthreads();
        {
            int idx = t;
#pragma unroll
            for (int r = 0; r < 4; r++, idx += 256) {
                int nl = idx >> 4, q = idx & 15;
                int node = n0 + nl; node = node < n ? node : n - 1;
                float4 a = ((const float4*)A)[(size_t)node * 32 + (kc >> 2) + q];
                *(float4*)&As[nl * 68 + q * 4] = a;
            }
        }
        {
            int idx = t;
#pragma unroll
            for (int r = 0; r < 4; r++, idx += 256) {
                int kl = idx >> 4, j4 = idx & 15;
                *(float4*)&W1s[kl * 68 + j4 * 4] = ((const float4*)WA)[(size_t)(kc + kl) * 16 + j4];
                *(float4*)&W2s[kl * 68 + j4 * 4] = ((const float4*)WB)[(size_t)(kc + kl) * 16 + j4];
            }
        }
        __syncthreads();

        const float* ap = &As[tn * 4 * 68];
        const float* w1p = &W1s[tj * 4];
        const float* w2p = &W2s[tj * 4];
#pragma unroll 2
        for (int k4 = 0; k4 < 16; k4++) {
            float4 a0 = *(const float4*)&ap[0 * 68 + k4 * 4];
            float4 a1 = *(const float4*)&ap[1 * 68 + k4 * 4];
            float4 a2 = *(const float4*)&ap[2 * 68 + k4 * 4];
            float4 a3 = *(const float4*)&ap[3 * 68 + k4 * 4];
#pragma unroll
            for (int kk = 0; kk < 4; kk++) {
                float4 w1 = *(const float4*)&w1p[(k4 * 4 + kk) * 68];
                float4 w2 = *(const float4*)&w2p[(k4 * 4 + kk) * 68];
                float av0 = kk == 0 ? a0.x : kk == 1 ? a0.y : kk == 2 ? a0.z : a0.w;
                float av1 = kk == 0 ? a1.x : kk == 1 ? a1.y : kk == 2 ? a1.z : a1.w;
                float av2 = kk == 0 ? a2.x : kk == 1 ? a2.y : kk == 2 ? a2.z : a2.w;
                float av3 = kk == 0 ? a3.x : kk == 1 ? a3.y : kk == 2 ? a3.z : a3.w;
#define FMA8(m, AV)                                                     \
                acc[m][0] += AV * w1.x; acc[m][1] += AV * w1.y;          \
                acc[m][2] += AV * w1.z; acc[m][3] += AV * w1.w;          \
                acc[m][4] += AV * w2.x; acc[m][5] += AV * w2.y;          \
                acc[m][6] += AV * w2.z; acc[m][7] += AV * w2.w;
                FMA8(0, av0)
                FMA8(1, av1)
                FMA8(2, av2)
                FMA8(3, av3)
#undef FMA8
            }
        }
    }

#pragma unroll
    for (int m = 0; m < 4; m++) {
        int node = n0 + tn * 4 + m;
        if (node < n) {
            *(float4*)&outA[(size_t)node * 64 + tj * 4] =
                make_float4(acc[m][0], acc[m][1], acc[m][2], acc[m][3]);
            *(float4*)&outB[(size_t)node * 64 + tj * 4] =
                make_float4(acc[m][4], acc[m][5], acc[m][6], acc[m][7]);
        }
    }
}

// ---------------- layer-2 GEMM: out = A @ [WA|WB], K=64, JW=32 ----------------
template<int K, int JW>
__global__ __launch_bounds__(256) void gemm_k(const float* __restrict__ A,
                                              const float* __restrict__ WA,
                                              const float* __restrict__ WB,
                                              float* __restrict__ out, int n) {
    __shared__ float As[64 * 68];
    __shared__ float Ws[64 * 68];
    const int t = threadIdx.x;
    const int tj = t & 15;
    const int tn = t >> 4;
    const int n0 = blockIdx.x * 64;
    float acc[4][4] = {};

    for (int kc = 0; kc < K; kc += 64) {
        if (kc) __syncthreads();
        {
            int idx = t;
#pragma unroll
            for (int r = 0; r < 4; r++, idx += 256) {
                int nl = idx >> 4, q = idx & 15;
                int node = n0 + nl; node = node < n ? node : n - 1;
                float4 a = ((const float4*)A)[(size_t)node * (K / 4) + (kc >> 2) + q];
                *(float4*)&As[nl * 68 + q * 4] = a;
            }
        }
        {
            int idx = t;
#pragma unroll
            for (int r = 0; r < 4; r++, idx += 256) {
                int kl = idx >> 4, j4 = idx & 15;
                const float* W = (j4 < 8) ? WA : WB;
                float4 w = ((const float4*)W)[(size_t)(kc + kl) * 8 + (j4 & 7)];
                *(float4*)&Ws[kl * 68 + j4 * 4] = w;
            }
        }
        __syncthreads();

        const float* ap = &As[tn * 4 * 68];
        const float* wp = &Ws[tj * 4];
#pragma unroll 4
        for (int k4 = 0; k4 < 16; k4++) {
            float4 a0 = *(const float4*)&ap[0 * 68 + k4 * 4];
            float4 a1 = *(const float4*)&ap[1 * 68 + k4 * 4];
            float4 a2 = *(const float4*)&ap[2 * 68 + k4 * 4];
            float4 a3 = *(const float4*)&ap[3 * 68 + k4 * 4];
            float4 w0 = *(const float4*)&wp[(k4 * 4 + 0) * 68];
            float4 w1 = *(const float4*)&wp[(k4 * 4 + 1) * 68];
            float4 w2 = *(const float4*)&wp[(k4 * 4 + 2) * 68];
            float4 w3 = *(const float4*)&wp[(k4 * 4 + 3) * 68];
#define FMA_ROW(m, AV)                                                   \
            acc[m][0] += AV.x * w0.x + AV.y * w1.x + AV.z * w2.x + AV.w * w3.x; \
            acc[m][1] += AV.x * w0.y + AV.y * w1.y + AV.z * w2.y + AV.w * w3.y; \
            acc[m][2] += AV.x * w0.z + AV.y * w1.z + AV.z * w2.z + AV.w * w3.z; \
            acc[m][3] += AV.x * w0.w + AV.y * w1.w + AV.z * w2.w + AV.w * w3.w;
            FMA_ROW(0, a0)
            FMA_ROW(1, a1)
            FMA_ROW(2, a2)
            FMA_ROW(3, a3)
#undef FMA_ROW
        }
    }

    int mat = tj >> 3;
    int jw = (tj & 7) * 4;
    float* ob = out + (size_t)mat * n * JW + jw;
#pragma unroll
    for (int m = 0; m < 4; m++) {
        int node = n0 + tn * 4 + m;
        if (node < n)
            *(float4*)&ob[(size_t)node * JW] =
                make_float4(acc[m][0], acc[m][1], acc[m][2], acc[m][3]);
    }
}

// ---------------- fused heads, 8 threads/node ----------------
__global__ __launch_bounds__(256) void heads_k(const float* __restrict__ h2,
                                               const float* __restrict__ Wp1, const float* __restrict__ bp1,
                                               const float* __restrict__ Wp2, const float* __restrict__ bp2,
                                               const float* __restrict__ Wc1, const float* __restrict__ bc1,
                                               const float* __restrict__ Wc2, const float* __restrict__ bc2,
                                               float* __restrict__ coord, float* __restrict__ z, int n) {
    __shared__ float sWp1[32 * 32], sWp2[32 * 32], sWc1[32 * 16], sWc2[32];
    __shared__ float sbp1[32], sbp2[32], sbc1[16], sbc2[2];
    __shared__ float sh[32 * 36], st[32 * 36], stc[32 * 18];
    const int t = threadIdx.x;
    for (int i = t; i < 1024; i += 256) { sWp1[i] = Wp1[i]; sWp2[i] = Wp2[i]; }
    for (int i = t; i < 512; i += 256) sWc1[i] = Wc1[i];
    if (t < 32) { sWc2[t] = Wc2[t]; sbp1[t] = bp1[t]; sbp2[t] = bp2[t]; }
    if (t < 16) sbc1[t] = bc1[t];
    if (t < 2) sbc2[t] = bc2[t];

    const int n0 = blockIdx.x * 32;
    const int nl = t >> 3;
    const int jq = t & 7;
    const int node = n0 + nl;
    {
        float4 v = make_float4(0.f, 0.f, 0.f, 0.f);
        if (node < n) v = *(const float4*)&h2[(size_t)node * 32 + jq * 4];
        *(float4*)&sh[nl * 36 + jq * 4] = v;
    }
    __syncthreads();

    float4 a = *(const float4*)&sbp1[jq * 4];
#pragma unroll
    for (int k = 0; k < 32; k++) {
        float hv = sh[nl * 36 + k];
        float4 w = *(const float4*)&sWp1[k * 32 + jq * 4];
        a.x += hv * w.x; a.y += hv * w.y; a.z += hv * w.z; a.w += hv * w.w;
    }
    a.x = fmaxf(a.x, 0.f); a.y = fmaxf(a.y, 0.f);
    a.z = fmaxf(a.z, 0.f); a.w = fmaxf(a.w, 0.f);
    *(float4*)&st[nl * 36 + jq * 4] = a;

    float2 c = *(const float2*)&sbc1[jq * 2];
#pragma unroll
    for (int k = 0; k < 32; k++) {
        float hv = sh[nl * 36 + k];
        float2 w = *(const float2*)&sWc1[k * 16 + jq * 2];
        c.x += hv * w.x; c.y += hv * w.y;
    }
    c.x = fmaxf(c.x, 0.f); c.y = fmaxf(c.y, 0.f);
    *(float2*)&stc[nl * 18 + jq * 2] = c;
    __syncthreads();

    float4 zz = *(const float4*)&sbp2[jq * 4];
#pragma unroll
    for (int k = 0; k < 32; k++) {
        float tv = st[nl * 36 + k];
        float4 w = *(const float4*)&sWp2[k * 32 + jq * 4];
        zz.x += tv * w.x; zz.y += tv * w.y; zz.z += tv * w.z; zz.w += tv * w.w;
    }
    if (node < n) *(float4*)&z[(size_t)node * 32 + jq * 4] = zz;

    if (jq < 2) {
        float s = sbc2[jq];
#pragma unroll
        for (int k = 0; k < 16; k++) s += stc[nl * 18 + k] * sWc2[k * 2 + jq];
        if (node < n) coord[(size_t)node * 2 + jq] = s;
    }
}

extern "C" void kernel_launch(void* const* d_in, const int* in_sizes, int n_in,
                              void* d_out, int out_size, void* d_ws, size_t ws_size,
                              hipStream_t stream) {
    const float* x    = (const float*)d_in[0];
    const int*   ei   = (const int*)d_in[1];
    const int*   src  = ei;
    const int*   dst  = ei + NE;
    const float* W1_1 = (const float*)d_in[2];
    const float* W1_2 = (const float*)d_in[3];
    const float* b1   = (const float*)d_in[4];
    const float* W2_1 = (const float*)d_in[5];
    const float* W2_2 = (const float*)d_in[6];
    const float* b2   = (const float*)d_in[7];
    const float* Wp1  = (const float*)d_in[8];
    const float* bp1  = (const float*)d_in[9];
    const float* Wp2  = (const float*)d_in[10];
    const float* bp2  = (const float*)d_in[11];
    const float* Wc1  = (const float*)d_in[12];
    const float* bc1  = (const float*)d_in[13];
    const float* Wc2  = (const float*)d_in[14];
    const float* bc2  = (const float*)d_in[15];

    // workspace layout (words: 50000+200000+200004+1024+800000+800000
    // = 2051028, %4 == 0 -> bufY 16B aligned)
    float* ws    = (float*)d_ws;
    float* dinv  = ws;                              // NN
    int*   cnt   = (int*)(dinv + NN);               // NN4
    int*   rowsS = cnt + NN4;                       // NN4+4 (padded)
    int*   bsum  = rowsS + NN4 + 4;                 // 1024
    int*   rank  = bsum + 1024;                     // NE
    int*   col   = rank + NE;                       // NE
    float* bufY  = (float*)(col + NE);              // NN*128 (16B aligned)
    float* bufZ  = bufY + (size_t)NN * 128;         // NN*64

    float* y1 = bufY;                       // NN*64   (then reused as u)
    float* y2 = bufY + (size_t)NN * 64;     // NN*64   (then reused as h1)
    float* u  = y1;
    float* h1 = y2;
    float* z1 = bufZ;                       // NN*32   (then reused as u2)
    float* z2 = bufZ + (size_t)NN * 32;     // NN*32   (then reused as h2)
    float* u2 = z1;
    float* h2 = z2;

    float* coord = (float*)d_out;                   // NN*2
    float* z     = (float*)d_out + 2 * NN;          // NN*32

    // 1) split-CSR build + dinv
    zero_cnt_k<<<NBLK2, 256, 0, stream>>>(cnt);
    hist_k<<<(NE + 255) / 256, 256, 0, stream>>>(src, dst, cnt, rank);
    sum_blocks_k<<<NBLK2, 256, 0, stream>>>(cnt, bsum, dinv);
    scan_blocks_k<<<1, 1024, 0, stream>>>(bsum, rowsS);
    scan_final_k<<<NBLK2, 256, 0, stream>>>(cnt, bsum, rowsS);
    scatter_k<<<(NE + 255) / 256, 256, 0, stream>>>(src, dst, rank, rowsS, col);

    // 2) [y1|y2] = x @ [W1_1|W1_2]   (K=128, both matrices in one pass)
    gemm1_k<<<(NN + 63) / 64, 256, 0, stream>>>(x, W1_1, W1_2, y1, y2, NN);
    // 3) u = y1 + P(y2)              (C=64)
    prop_k<4, true><<<(NN * 16 + 255) / 256, 256, 0, stream>>>(
        (const float4*)y2, (const float4*)y1, nullptr, (float4*)u, rowsS, col, dinv);
    // 4) h1 = relu(P(u) + b1)        (C=64)
    prop_k<4, false><<<(NN * 16 + 255) / 256, 256, 0, stream>>>(
        (const float4*)u, nullptr, b1, (float4*)h1, rowsS, col, dinv);
    // 5) [z1|z2] = h1 @ [W2_1|W2_2]  (K=64, one block spans both 32-wide mats)
    gemm_k<64, 32><<<(NN + 63) / 64, 256, 0, stream>>>(h1, W2_1, W2_2, bufZ, NN);
    // 6) u2 = z1 + P(z2)             (C=32)
    prop_k<3, true><<<(NN * 8 + 255) / 256, 256, 0, stream>>>(
        (const float4*)z2, (const float4*)z1, nullptr, (float4*)u2, rowsS, col, dinv);
    // 7) h2 = relu(P(u2) + b2)       (C=32)
    prop_k<3, false><<<(NN * 8 + 255) / 256, 256, 0, stream>>>(
        (const float4*)u2, nullptr, b2, (float4*)h2, rowsS, col, dinv);
    // 8) heads (8 threads/node)
    heads_k<<<(NN + 31) / 32, 256, 0, stream>>>(h2, Wp1, bp1, Wp2, bp2, Wc1, bc1, Wc2, bc2, coord, z, NN);
}